// Round 2
// baseline (2027.820 us; speedup 1.0000x reference)
//
#include <hip/hip_runtime.h>
#include <hip/hip_bf16.h>

typedef __hip_bfloat16 bf16_t;

static __device__ __forceinline__ float b2f(bf16_t v) { return __bfloat162float(v); }
static __device__ __forceinline__ bf16_t f2b(float v) { return __float2bfloat16(v); }

// Problem constants (fixed by the reference)
#define NN 50000
#define EE 200000
#define GG 2048

// ---------------------------------------------------------------------------
// Edge scatter-add:  agg[dst] += src_data[src]   (width W features per node)
// one thread per (edge, feature)
// ---------------------------------------------------------------------------
template <int W>
__global__ void scatter_add_f32(const int* __restrict__ ei,
                                const float* __restrict__ src_data,
                                float* __restrict__ agg, int E) {
    int t = blockIdx.x * blockDim.x + threadIdx.x;
    if (t >= E * W) return;
    int e = t / W;
    int f = t - e * W;
    int s = ei[e];
    int d = ei[E + e];
    unsafeAtomicAdd(agg + d * W + f, src_data[s * W + f]);
}

// ---------------------------------------------------------------------------
// GEMM A (wide output):  out[n,o] = relu(bias[o] + sum_k A1[n,k]*Wrel[o,k]
//                                                + sum_k A2[n,k]*Wroot[o,k])
// A1,A2 fp32 [N,K], weights fp32 [O,K], out bf16 [N,O]
// Tile: 64x64, block 16x16 threads, 4x4 micro-tile, K-chunks of 32.
// K1,K2 multiples of 32 (64 or 128 here).
// ---------------------------------------------------------------------------
#define KC 32
#define BM 64
#define BN 64
#define LDSTR 68   // padded leading dim: staging conflicts <=4-way, reads conflict-free

__global__ __launch_bounds__(256) void gemmA(
    const float* __restrict__ A1, const float* __restrict__ A2,
    const float* __restrict__ Wrel, const float* __restrict__ Wroot,
    const float* __restrict__ bias, bf16_t* __restrict__ out,
    int Nn, int O, int K1, int K2) {
    __shared__ float As[KC][LDSTR];
    __shared__ float Wsh[KC][LDSTR];
    const int tid = threadIdx.y * 16 + threadIdx.x;
    const int bm0 = blockIdx.y * BM;
    const int bn0 = blockIdx.x * BN;
    const int Ktot = K1 + K2;
    float acc[4][4] = {};

    for (int kc0 = 0; kc0 < Ktot; kc0 += KC) {
        const bool fromA1 = (kc0 < K1);
#pragma unroll
        for (int i = 0; i < (BM * KC) / 256; ++i) {
            int e = i * 256 + tid;
            int k = e & (KC - 1);
            int m = e >> 5;  // e / KC
            int row = bm0 + m;
            if (row >= Nn) row = Nn - 1;
            float v;
            if (fromA1) v = A1[row * K1 + kc0 + k];
            else        v = A2[row * K2 + (kc0 - K1) + k];
            As[k][m] = v;
            int o = bn0 + m;
            if (o >= O) o = O - 1;
            float w;
            if (fromA1) w = Wrel[o * K1 + kc0 + k];
            else        w = Wroot[o * K2 + (kc0 - K1) + k];
            Wsh[k][m] = w;
        }
        __syncthreads();
#pragma unroll
        for (int k = 0; k < KC; ++k) {
            float a[4], w[4];
#pragma unroll
            for (int i = 0; i < 4; ++i) a[i] = As[k][threadIdx.y * 4 + i];
#pragma unroll
            for (int j = 0; j < 4; ++j) w[j] = Wsh[k][threadIdx.x * 4 + j];
#pragma unroll
            for (int i = 0; i < 4; ++i)
#pragma unroll
                for (int j = 0; j < 4; ++j)
                    acc[i][j] = fmaf(a[i], w[j], acc[i][j]);
        }
        __syncthreads();
    }

#pragma unroll
    for (int i = 0; i < 4; ++i) {
        int row = bm0 + threadIdx.y * 4 + i;
        if (row >= Nn) continue;
#pragma unroll
        for (int j = 0; j < 4; ++j) {
            int col = bn0 + threadIdx.x * 4 + j;
            if (col < O) {
                float v = acc[i][j] + bias[col];
                out[row * O + col] = f2b(fmaxf(v, 0.f));
            }
        }
    }
}

// ---------------------------------------------------------------------------
// GEMM B (narrow output, two weight mats):
//   y[n,o]   = sum_k A[n,k]*Wrel[o,k]            (col o < O)     -> fp32 buffer
//   agg[n,o] = sum_k A[n,k]*Wroot[o,k] + bias[o] (col >= O)      -> init for scatter
// A bf16 [N,K] (K=1000), weights fp32, column space = 2*O (multiple of 64).
// ---------------------------------------------------------------------------
__global__ __launch_bounds__(256) void gemmB(
    const bf16_t* __restrict__ A, const float* __restrict__ Wrel,
    const float* __restrict__ Wroot, const float* __restrict__ bias,
    float* __restrict__ y, float* __restrict__ agg, int Nn, int K, int O) {
    __shared__ float As[KC][LDSTR];
    __shared__ float Wsh[KC][LDSTR];
    const int tid = threadIdx.y * 16 + threadIdx.x;
    const int bm0 = blockIdx.y * BM;
    const int bn0 = blockIdx.x * BN;
    float acc[4][4] = {};

    for (int kc0 = 0; kc0 < K; kc0 += KC) {
#pragma unroll
        for (int i = 0; i < (BM * KC) / 256; ++i) {
            int e = i * 256 + tid;
            int k = e & (KC - 1);
            int m = e >> 5;
            int row = bm0 + m;
            if (row >= Nn) row = Nn - 1;
            int kk = kc0 + k;
            As[k][m] = (kk < K) ? b2f(A[row * K + kk]) : 0.f;
            int o2 = bn0 + m;
            const float* Wp = (o2 < O) ? Wrel : Wroot;
            int oo = (o2 < O) ? o2 : (o2 - O);
            Wsh[k][m] = (kk < K) ? Wp[oo * K + kk] : 0.f;
        }
        __syncthreads();
#pragma unroll
        for (int k = 0; k < KC; ++k) {
            float a[4], w[4];
#pragma unroll
            for (int i = 0; i < 4; ++i) a[i] = As[k][threadIdx.y * 4 + i];
#pragma unroll
            for (int j = 0; j < 4; ++j) w[j] = Wsh[k][threadIdx.x * 4 + j];
#pragma unroll
            for (int i = 0; i < 4; ++i)
#pragma unroll
                for (int j = 0; j < 4; ++j)
                    acc[i][j] = fmaf(a[i], w[j], acc[i][j]);
        }
        __syncthreads();
    }

#pragma unroll
    for (int i = 0; i < 4; ++i) {
        int row = bm0 + threadIdx.y * 4 + i;
        if (row >= Nn) continue;
#pragma unroll
        for (int j = 0; j < 4; ++j) {
            int c = bn0 + threadIdx.x * 4 + j;
            if (c < O) {
                y[row * O + c] = acc[i][j];
            } else {
                int cc = c - O;
                agg[row * O + cc] = acc[i][j] + bias[cc];
            }
        }
    }
}

// ---------------------------------------------------------------------------
// Elementwise: relu fp32 -> fp32
// ---------------------------------------------------------------------------
__global__ void relu_f32(const float* __restrict__ in,
                         float* __restrict__ out, int n) {
    int t = blockIdx.x * blockDim.x + threadIdx.x;
    if (t < n) out[t] = fmaxf(in[t], 0.f);
}

// ---------------------------------------------------------------------------
// Mean-pool per graph: batch is sorted; binary search the node range.
// One block (128 threads = 128 features) per graph.
// ---------------------------------------------------------------------------
__global__ void pool_kernel(const float* __restrict__ h2,
                            const int* __restrict__ batch,
                            float* __restrict__ enc, int Nn) {
    int g = blockIdx.x;
    __shared__ int s_lo, s_hi;
    if (threadIdx.x == 0) {
        int lo = 0, hi = Nn;
        while (lo < hi) { int mid = (lo + hi) >> 1; if (batch[mid] < g) lo = mid + 1; else hi = mid; }
        s_lo = lo;
        hi = Nn;
        while (lo < hi) { int mid = (lo + hi) >> 1; if (batch[mid] < g + 1) lo = mid + 1; else hi = mid; }
        s_hi = lo;
    }
    __syncthreads();
    int f = threadIdx.x;
    float sum = 0.f;
    for (int n = s_lo; n < s_hi; ++n) sum += h2[n * 128 + f];
    float cnt = (float)((s_hi - s_lo) > 0 ? (s_hi - s_lo) : 1);
    enc[g * 128 + f] = sum / cnt;
}

// ---------------------------------------------------------------------------
// Launch
// ---------------------------------------------------------------------------
extern "C" void kernel_launch(void* const* d_in, const int* in_sizes, int n_in,
                              void* d_out, int out_size, void* d_ws, size_t ws_size,
                              hipStream_t stream) {
    const float* x       = (const float*)d_in[0];
    const int*   ei      = (const int*)d_in[1];
    const int*   batch   = (const int*)d_in[2];
    const float* W1_rel  = (const float*)d_in[3];
    const float* b1      = (const float*)d_in[4];
    const float* W1_root = (const float*)d_in[5];
    const float* W2_rel  = (const float*)d_in[6];
    const float* b2      = (const float*)d_in[7];
    const float* W2_root = (const float*)d_in[8];
    const float* W3_rel  = (const float*)d_in[9];
    const float* b3      = (const float*)d_in[10];
    const float* W3_root = (const float*)d_in[11];
    const float* W4_rel  = (const float*)d_in[12];
    const float* b4      = (const float*)d_in[13];
    const float* W4_root = (const float*)d_in[14];

    float* outF = (float*)d_out;            // [N,64] then [G,128]
    float* enc  = outF + NN * 64;

    char* ws = (char*)d_ws;
    // Workspace layout (≈190 MB):
    bf16_t* h_big = (bf16_t*)(ws + 0);            // [N,1000] bf16 (h1 then h3)
    float*  aggA  = (float*)(ws + 100000128ULL);  // [N,64]  f32 (layer-1 agg)
    float*  ybuf  = (float*)(ws + 112800128ULL);  // [N,128] f32 (y2, then y4)
    float*  aggB  = (float*)(ws + 138400128ULL);  // [N,128] f32 (layer-2 agg, then layer-3 agg)
    float*  h2buf = (float*)(ws + 164000128ULL);  // [N,128] f32

    dim3 blk2(16, 16);
    dim3 gridA(16, (NN + BM - 1) / BM);   // O=1000 -> 16 col blocks (1024 cols, guarded)
    dim3 gridB2(4, (NN + BM - 1) / BM);   // 2*128/64
    dim3 gridB4(2, (NN + BM - 1) / BM);   // 2*64/64

    // ---- Layer 1: aggx = scatter(x);  h1 = relu([aggx|x] @ [W1_rel|W1_root]^T + b1)
    hipMemsetAsync(aggA, 0, (size_t)NN * 64 * 4, stream);
    scatter_add_f32<64><<<(EE * 64 + 255) / 256, 256, 0, stream>>>(ei, x, aggA, EE);
    gemmA<<<gridA, blk2, 0, stream>>>(aggA, x, W1_rel, W1_root, b1, h_big, NN, 1000, 64, 64);

    // ---- Layer 2: y2 = h1@W2_rel^T; aggB = h1@W2_root^T + b2; aggB += scatter(y2); h2 = relu(aggB)
    gemmB<<<gridB2, blk2, 0, stream>>>(h_big, W2_rel, W2_root, b2, ybuf, aggB, NN, 1000, 128);
    scatter_add_f32<128><<<(EE * 128 + 255) / 256, 256, 0, stream>>>(ei, ybuf, aggB, EE);
    relu_f32<<<(NN * 128 + 255) / 256, 256, 0, stream>>>(aggB, h2buf, NN * 128);

    // ---- encoded = mean-pool(h2) per graph
    pool_kernel<<<GG, 128, 0, stream>>>(h2buf, batch, enc, NN);

    // ---- Layer 3: aggh2 = scatter(h2); h3 = relu([aggh2|h2] @ [W3_rel|W3_root]^T + b3)
    hipMemsetAsync(aggB, 0, (size_t)NN * 128 * 4, stream);
    scatter_add_f32<128><<<(EE * 128 + 255) / 256, 256, 0, stream>>>(ei, h2buf, aggB, EE);
    gemmA<<<gridA, blk2, 0, stream>>>(aggB, h2buf, W3_rel, W3_root, b3, h_big, NN, 1000, 128, 128);

    // ---- Layer 4: out = h3@W4_root^T + b4 (direct into d_out) + scatter(h3@W4_rel^T)
    gemmB<<<gridB4, blk2, 0, stream>>>(h_big, W4_rel, W4_root, b4, ybuf, outF, NN, 1000, 64);
    scatter_add_f32<64><<<(EE * 64 + 255) / 256, 256, 0, stream>>>(ei, ybuf, outF, EE);
}

// Round 3
// 758.020 us; speedup vs baseline: 2.6752x; 2.6752x over previous
//
#include <hip/hip_runtime.h>
#include <hip/hip_bf16.h>

typedef __hip_bfloat16 bf16_t;
typedef __attribute__((ext_vector_type(8))) short short8;
typedef __attribute__((ext_vector_type(4))) float floatx4;

static __device__ __forceinline__ float b2f(bf16_t v) { return __bfloat162float(v); }
static __device__ __forceinline__ bf16_t f2b(float v) { return __float2bfloat16(v); }

// Problem constants
#define NN 50000
#define EE 200000
#define GG 2048

// ---------------------------------------------------------------------------
// Edge scatter-add:  agg[dst] += src_data[src]
// ---------------------------------------------------------------------------
template <int W>
__global__ void scatter_add_f32(const int* __restrict__ ei,
                                const float* __restrict__ src_data,
                                float* __restrict__ agg, int E) {
    int t = blockIdx.x * blockDim.x + threadIdx.x;
    if (t >= E * W) return;
    int e = t / W;
    int f = t - e * W;
    int s = ei[e];
    int d = ei[E + e];
    unsafeAtomicAdd(agg + d * W + f, src_data[s * W + f]);
}

// ---------------------------------------------------------------------------
// MFMA GEMM:  C[n, col] = sum_k A[n,k] * W[col,k]   (A,W bf16, K-major)
// Block tile 128x128, 4 waves in 2x2, each wave 64x64 via 16x16x32 bf16 MFMA.
// BK=64. LDS granule-XOR swizzle: element (row, k) lives at
//   lds[row*64 + (g ^ (row&7))*8 + (k%8)]  where g = k/8 within the chunk.
// Staging writes (b128) and fragment reads (b128) are both conflict-free.
// Requires: K % 64 == 0; W has gridDim.x*128 rows (zero-padded).
// mode 0: out0[row*ostride0+col] = col<Ocols ? relu(acc+bias[col]) : 0
// mode 1: col<Osplit -> y1[row*Osplit+col]=acc ; else agg1[...]=acc+bias
// ---------------------------------------------------------------------------
#define GBM 128
#define GBN 128
#define GBK 64

__global__ __launch_bounds__(256) void mfma_gemm(
    const bf16_t* __restrict__ A, const bf16_t* __restrict__ W,
    const float* __restrict__ bias,
    bf16_t* __restrict__ out0, int ostride0, int Ocols,
    float* __restrict__ y1, float* __restrict__ agg1, int Osplit,
    int Nn, int K, int mode)
{
    __shared__ bf16_t Asl[GBM * GBK];   // 16 KB
    __shared__ bf16_t Bsl[GBN * GBK];   // 16 KB

    const int tid  = threadIdx.x;
    const int lane = tid & 63;
    const int wave = tid >> 6;
    const int wm = wave & 1;
    const int wn = wave >> 1;
    const int bm0 = blockIdx.y * GBM;
    const int bn0 = blockIdx.x * GBN;

    // Staging map: granule flat = i*256+tid -> row=flat/8, g=flat%8
    int aoff_lds[4];
    int agoff[4], bgoff[4];   // element offsets (k0 added in loop)
    #pragma unroll
    for (int i = 0; i < 4; ++i) {
        int flat = i * 256 + tid;
        int row = flat >> 3;
        int g = flat & 7;
        int s = g ^ (row & 7);
        aoff_lds[i] = row * GBK + s * 8;
        int gr = bm0 + row; if (gr > Nn - 1) gr = Nn - 1;   // clamp (dup reads ok)
        agoff[i] = gr * K + g * 8;
        bgoff[i] = (bn0 + row) * K + g * 8;                 // W rows are padded
    }

    floatx4 acc[4][4];
    #pragma unroll
    for (int mi = 0; mi < 4; ++mi)
        #pragma unroll
        for (int ni = 0; ni < 4; ++ni)
            acc[mi][ni] = (floatx4){0.f, 0.f, 0.f, 0.f};

    const int frow = lane & 15;
    const int quad = lane >> 4;

    for (int k0 = 0; k0 < K; k0 += GBK) {
        #pragma unroll
        for (int i = 0; i < 4; ++i) {
            uint4 va = *(const uint4*)(A + agoff[i] + k0);
            uint4 vb = *(const uint4*)(W + bgoff[i] + k0);
            *(uint4*)(&Asl[aoff_lds[i]]) = va;
            *(uint4*)(&Bsl[aoff_lds[i]]) = vb;
        }
        __syncthreads();
        #pragma unroll
        for (int ks = 0; ks < 2; ++ks) {
            short8 afr[4], bfr[4];
            #pragma unroll
            for (int mi = 0; mi < 4; ++mi) {
                int row = wm * 64 + mi * 16 + frow;
                int s = (ks * 4 + quad) ^ (row & 7);
                afr[mi] = *(const short8*)(&Asl[row * GBK + s * 8]);
            }
            #pragma unroll
            for (int ni = 0; ni < 4; ++ni) {
                int row = wn * 64 + ni * 16 + frow;
                int s = (ks * 4 + quad) ^ (row & 7);
                bfr[ni] = *(const short8*)(&Bsl[row * GBK + s * 8]);
            }
            #pragma unroll
            for (int mi = 0; mi < 4; ++mi)
                #pragma unroll
                for (int ni = 0; ni < 4; ++ni)
                    acc[mi][ni] = __builtin_amdgcn_mfma_f32_16x16x32_bf16(
                        afr[mi], bfr[ni], acc[mi][ni], 0, 0, 0);
        }
        __syncthreads();
    }

    // Epilogue. C/D map: col = lane&15, row = (lane>>4)*4 + reg
    #pragma unroll
    for (int mi = 0; mi < 4; ++mi) {
        #pragma unroll
        for (int r = 0; r < 4; ++r) {
            int grow = bm0 + wm * 64 + mi * 16 + quad * 4 + r;
            if (grow >= Nn) continue;
            #pragma unroll
            for (int ni = 0; ni < 4; ++ni) {
                int gcol = bn0 + wn * 64 + ni * 16 + frow;
                float v = acc[mi][ni][r];
                if (mode == 0) {
                    bf16_t o = f2b(0.f);
                    if (gcol < Ocols) o = f2b(fmaxf(v + bias[gcol], 0.f));
                    out0[grow * ostride0 + gcol] = o;
                } else {
                    if (gcol < Osplit) y1[grow * Osplit + gcol] = v;
                    else agg1[grow * Osplit + (gcol - Osplit)] = v + bias[gcol - Osplit];
                }
            }
        }
    }
}

// ---------------------------------------------------------------------------
// Weight packers (run every call; tiny). All outputs zero-padded bf16.
// ---------------------------------------------------------------------------
// Wcat[r][k] (Rpad x Kpad): k<K1 from Wa[r][k], K1<=k<K1+K2 from Wb[r][k-K1]
__global__ void pack_w_k(const float* __restrict__ Wa, const float* __restrict__ Wb,
                         bf16_t* __restrict__ out, int R, int Rpad,
                         int K1, int K2, int Kpad) {
    int idx = blockIdx.x * 256 + threadIdx.x;
    if (idx >= Rpad * Kpad) return;
    int r = idx / Kpad, k = idx - r * Kpad;
    float v = 0.f;
    if (r < R) {
        if (k < K1) v = Wa[r * K1 + k];
        else if (k < K1 + K2) v = Wb[r * K2 + (k - K1)];
    }
    out[idx] = f2b(v);
}
// Wcat rows [0,Ra) from Wa, [Ra,Ra+Rb) from Wb; K -> Kpad zero-padded
__global__ void pack_w_r(const float* __restrict__ Wa, const float* __restrict__ Wb,
                         bf16_t* __restrict__ out, int Ra, int Rb, int K, int Kpad) {
    int idx = blockIdx.x * 256 + threadIdx.x;
    if (idx >= (Ra + Rb) * Kpad) return;
    int r = idx / Kpad, k = idx - r * Kpad;
    float v = 0.f;
    if (k < K) v = (r < Ra) ? Wa[r * K + k] : Wb[(r - Ra) * K + k];
    out[idx] = f2b(v);
}
// A-cat: out[n][k] (bf16, width 2*Kc) = k<Kc ? A1[n][k] : A2[n][k-Kc]
__global__ void cat2_bf16(const float* __restrict__ A1, const float* __restrict__ A2,
                          bf16_t* __restrict__ out, int total, int Kc) {
    int idx = blockIdx.x * 256 + threadIdx.x;
    if (idx >= total) return;
    int K2 = 2 * Kc;
    int r = idx / K2, k = idx - r * K2;
    out[idx] = f2b(k < Kc ? A1[r * Kc + k] : A2[r * Kc + (k - Kc)]);
}

__global__ void relu_f32(const float* __restrict__ in, float* __restrict__ out, int n) {
    int t = blockIdx.x * blockDim.x + threadIdx.x;
    if (t < n) out[t] = fmaxf(in[t], 0.f);
}

// ---------------------------------------------------------------------------
// Mean-pool per graph (batch sorted; binary search)
// ---------------------------------------------------------------------------
__global__ void pool_kernel(const float* __restrict__ h2,
                            const int* __restrict__ batch,
                            float* __restrict__ enc, int Nn) {
    int g = blockIdx.x;
    __shared__ int s_lo, s_hi;
    if (threadIdx.x == 0) {
        int lo = 0, hi = Nn;
        while (lo < hi) { int mid = (lo + hi) >> 1; if (batch[mid] < g) lo = mid + 1; else hi = mid; }
        s_lo = lo;
        hi = Nn;
        while (lo < hi) { int mid = (lo + hi) >> 1; if (batch[mid] < g + 1) lo = mid + 1; else hi = mid; }
        s_hi = lo;
    }
    __syncthreads();
    int f = threadIdx.x;
    float sum = 0.f;
    for (int n = s_lo; n < s_hi; ++n) sum += h2[n * 128 + f];
    float cnt = (float)((s_hi - s_lo) > 0 ? (s_hi - s_lo) : 1);
    enc[g * 128 + f] = sum / cnt;
}

// ---------------------------------------------------------------------------
// Launch
// ---------------------------------------------------------------------------
extern "C" void kernel_launch(void* const* d_in, const int* in_sizes, int n_in,
                              void* d_out, int out_size, void* d_ws, size_t ws_size,
                              hipStream_t stream) {
    const float* x       = (const float*)d_in[0];
    const int*   ei      = (const int*)d_in[1];
    const int*   batch   = (const int*)d_in[2];
    const float* W1_rel  = (const float*)d_in[3];
    const float* b1      = (const float*)d_in[4];
    const float* W1_root = (const float*)d_in[5];
    const float* W2_rel  = (const float*)d_in[6];
    const float* b2      = (const float*)d_in[7];
    const float* W2_root = (const float*)d_in[8];
    const float* W3_rel  = (const float*)d_in[9];
    const float* b3      = (const float*)d_in[10];
    const float* W3_root = (const float*)d_in[11];
    const float* W4_rel  = (const float*)d_in[12];
    const float* b4      = (const float*)d_in[13];
    const float* W4_root = (const float*)d_in[14];

    float* outF = (float*)d_out;            // [N,64] then [G,128]
    float* enc  = outF + NN * 64;

    char* ws = (char*)d_ws;
    // Workspace (~181 MB), region R1 time-multiplexed:
    bf16_t* h_big = (bf16_t*)(ws + 0);             // [N][1024] bf16, 102.4 MB (h1 then h3)
    char*   R1    = ws + 102400000ULL;             // 25.6 MB multi-use
    float*  aggA  = (float*)R1;                    //   step1: [N,64] f32 agg
    bf16_t* A1cat = (bf16_t*)(R1 + 12800000ULL);   //   step1: [N,128] bf16
    float*  ybuf  = (float*)R1;                    //   step2: [N,128] f32 y2
    bf16_t* A3cat = (bf16_t*)R1;                   //   step4: [N,256] bf16
    float*  y4    = (float*)R1;                    //   step5: [N,64] f32
    float*  aggB  = (float*)(ws + 128000000ULL);   // [N,128] f32 (L2 agg, then L3 agg)
    float*  h2buf = (float*)(ws + 153600000ULL);   // [N,128] f32
    bf16_t* W1cat = (bf16_t*)(ws + 179200000ULL);  // [1024][128]
    bf16_t* W2cat = (bf16_t*)(ws + 179462144ULL);  // [256][1024]
    bf16_t* W3cat = (bf16_t*)(ws + 179986432ULL);  // [1024][256]
    bf16_t* W4cat = (bf16_t*)(ws + 180510720ULL);  // [128][1024]

    const int RB = (NN + GBM - 1) / GBM;  // 391 row blocks

    // ---- pack weights to bf16 (tiny)
    pack_w_k<<<(1024 * 128 + 255) / 256, 256, 0, stream>>>(W1_rel, W1_root, W1cat, 1000, 1024, 64, 64, 128);
    pack_w_r<<<(256 * 1024 + 255) / 256, 256, 0, stream>>>(W2_rel, W2_root, W2cat, 128, 128, 1000, 1024);
    pack_w_k<<<(1024 * 256 + 255) / 256, 256, 0, stream>>>(W3_rel, W3_root, W3cat, 1000, 1024, 128, 128, 256);
    pack_w_r<<<(128 * 1024 + 255) / 256, 256, 0, stream>>>(W4_rel, W4_root, W4cat, 64, 64, 1000, 1024);

    // ---- Layer 1: aggA = scatter(x); h1 = relu([aggA|x] @ W1cat^T + b1) -> h_big
    hipMemsetAsync(aggA, 0, (size_t)NN * 64 * 4, stream);
    scatter_add_f32<64><<<(EE * 64 + 255) / 256, 256, 0, stream>>>(ei, x, aggA, EE);
    cat2_bf16<<<(NN * 128 + 255) / 256, 256, 0, stream>>>(aggA, x, A1cat, NN * 128, 64);
    mfma_gemm<<<dim3(8, RB), 256, 0, stream>>>(A1cat, W1cat, b1,
        h_big, 1024, 1000, nullptr, nullptr, 0, NN, 128, 0);

    // ---- Layer 2: [y2 | agg-init] = h1 @ W2cat^T; scatter(y2)+=aggB; h2 = relu(aggB)
    mfma_gemm<<<dim3(2, RB), 256, 0, stream>>>(h_big, W2cat, b2,
        nullptr, 0, 0, ybuf, aggB, 128, NN, 1024, 1);
    scatter_add_f32<128><<<(EE * 128 + 255) / 256, 256, 0, stream>>>(ei, ybuf, aggB, EE);
    relu_f32<<<(NN * 128 + 255) / 256, 256, 0, stream>>>(aggB, h2buf, NN * 128);

    // ---- encoded = mean-pool(h2)
    pool_kernel<<<GG, 128, 0, stream>>>(h2buf, batch, enc, NN);

    // ---- Layer 3: aggB = scatter(h2); h3 = relu([aggB|h2] @ W3cat^T + b3) -> h_big
    hipMemsetAsync(aggB, 0, (size_t)NN * 128 * 4, stream);
    scatter_add_f32<128><<<(EE * 128 + 255) / 256, 256, 0, stream>>>(ei, h2buf, aggB, EE);
    cat2_bf16<<<(NN * 256 + 255) / 256, 256, 0, stream>>>(aggB, h2buf, A3cat, NN * 256, 128);
    mfma_gemm<<<dim3(8, RB), 256, 0, stream>>>(A3cat, W3cat, b3,
        h_big, 1024, 1000, nullptr, nullptr, 0, NN, 256, 0);

    // ---- Layer 4: [y4 | out-init] = h3 @ W4cat^T; out += scatter(y4)
    mfma_gemm<<<dim3(1, RB), 256, 0, stream>>>(h_big, W4cat, b4,
        nullptr, 0, 0, y4, outF, 64, NN, 1024, 1);
    scatter_add_f32<64><<<(EE * 64 + 255) / 256, 256, 0, stream>>>(ei, y4, outF, EE);
}